// Round 15
// baseline (73.299 us; speedup 1.0000x reference)
//
#include <hip/hip_runtime.h>

// GGCARAFE: gradient-guided CARAFE upsample, B=8, C=256, H=W=64, K=3, S=2
// R15 = R13 + ONE change: k_fused Phase B stores f4 (16B/lane, 1KB/wave —
// matches fillBuffer's 6.9 TB/s pattern) via (p_=l>>5, wp=l&31) lane map.
// Patch via 3 coalesced row loads + 12 clamped shfls (no extra requests).
// R14 lesson: L2-thrash theory dead (shfl-loads + nt stores both neutral).
// ws layout (float indices):
//   w1bf  [64][256] bf16        @ 0       (8192 f32-equiv)
//   mean  [B][H][W] f32         @ 8192    (32768)
//   w2b   [48][576] bf16        @ 40960   (13824 f32-equiv)
//   comp_p[8][66][66][64] bf16  @ 54784   (1115136 f32-equiv) zero ring
// total 1,169,920 floats = 4.68 MB

#define W1BF_OFF  0
#define MEAN_OFF  8192
#define W2B_OFF   40960
#define CPP_OFF   54784

typedef __attribute__((ext_vector_type(8))) short bf8;            // 8 bf16 = 16B
typedef __attribute__((ext_vector_type(8))) unsigned short us8;   // 16B store
typedef __attribute__((ext_vector_type(4))) float f4;
typedef __attribute__((ext_vector_type(2))) float f2;

static __device__ inline unsigned short f2bf(float f) {
    unsigned u = __float_as_uint(f);
    unsigned r = u + 0x7FFFu + ((u >> 16) & 1u);   // RNE
    return (unsigned short)(r >> 16);
}

// k_init: zero comp_p PAD RING only + weight converts/transposes.
__global__ __launch_bounds__(256) void k_init(const float* __restrict__ w1,
                                              const float* __restrict__ w2,
                                              float* __restrict__ ws) {
    int bid = blockIdx.x, t = threadIdx.x;
    if (bid < 65) {
        int id = bid * 256 + t;           // 0..16639
        if (id < 16640) {
            int px = id >> 3, part = id & 7;
            int b = px / 260, r = px % 260;
            int y, xx;
            if (r < 66)       { y = 0;  xx = r; }
            else if (r < 132) { y = 65; xx = r - 66; }
            else              { int s = r - 132; y = (s & 63) + 1; xx = (s >> 6) ? 65 : 0; }
            uint4* p = (uint4*)((unsigned short*)(ws + CPP_OFF)
                                + ((size_t)(b * 66 + y) * 66 + xx) * 64) + part;
            *p = uint4{0, 0, 0, 0};
        }
        return;
    }
    unsigned short* w1bf = (unsigned short*)(ws + W1BF_OFF);
    unsigned short* w2b  = (unsigned short*)(ws + W2B_OFF);
    int gid = (bid - 65) * 256 + t;
    int stride = 68 * 256;
    for (int i = gid; i < 64 * 256; i += stride)         // direct convert
        w1bf[i] = f2bf(w1[i]);
    for (int i = gid; i < 48 * 576; i += stride) {       // w2b[o][s*64+j]
        int o = i / 576, k = i % 576;
        int s = k >> 6, j = k & 63;
        w2b[i] = (o < 36) ? f2bf(w2[o * 576 + j * 9 + s]) : (unsigned short)0;
    }
}

// comp GEMM (R13 proven): grid 512 = (b,h); block 256 = 4 waves.
__global__ __launch_bounds__(256) void k_comp(const float* __restrict__ x,
                                              const float* __restrict__ b1,
                                              float* __restrict__ ws) {
    const unsigned short* w1bf = (const unsigned short*)(ws + W1BF_OFF);
    float* mean = ws + MEAN_OFF;
    unsigned short* cpp = (unsigned short*)(ws + CPP_OFF);
    __shared__ unsigned short xbf[64][260];   // 33.3 KB (+4 pad)
    __shared__ float msp[16][64];             // 4 KB mean partials
    __shared__ float ctile[64][68];           // 17.4 KB epilogue staging

    int bid = blockIdx.x;
    int b = bid >> 6, h = bid & 63;
    int t = threadIdx.x;

    int cg = t >> 4;
    int px4 = (t & 15) * 4;
    float ms0 = 0.f, ms1 = 0.f, ms2 = 0.f, ms3 = 0.f;
    const float* xb = x + (size_t)b * 256 * 4096 + h * 64;
#pragma unroll
    for (int it = 0; it < 16; it++) {
        int c = it * 16 + cg;
        f4 v = *(const f4*)(xb + (size_t)c * 4096 + px4);
        ms0 += v[0]; ms1 += v[1]; ms2 += v[2]; ms3 += v[3];
        xbf[px4 + 0][c] = f2bf(v[0]);
        xbf[px4 + 1][c] = f2bf(v[1]);
        xbf[px4 + 2][c] = f2bf(v[2]);
        xbf[px4 + 3][c] = f2bf(v[3]);
    }
    msp[cg][px4 + 0] = ms0; msp[cg][px4 + 1] = ms1;
    msp[cg][px4 + 2] = ms2; msp[cg][px4 + 3] = ms3;
    __syncthreads();
    if (t < 64) {
        float s = 0.f;
#pragma unroll
        for (int k2 = 0; k2 < 16; k2++) s += msp[k2][t];
        mean[(b * 64 + h) * 64 + t] = s * (1.f / 256.f);
    }

    int wid = __builtin_amdgcn_readfirstlane(t >> 6);  // 0..3
    int l = t & 63, lm = l & 15, lk = l >> 4;
    bf8 bfrag[8];
    const unsigned short* wp = w1bf + (size_t)(wid * 16 + lm) * 256 + lk * 8;
#pragma unroll
    for (int ks = 0; ks < 8; ks++) bfrag[ks] = *(const bf8*)(wp + ks * 32);
    float bb = b1[wid * 16 + lm];
#pragma unroll
    for (int mt = 0; mt < 4; mt++) {
        f4 acc = {bb, bb, bb, bb};
#pragma unroll
        for (int ks = 0; ks < 8; ks++) {
            bf8 af = *(const bf8*)(&xbf[mt * 16 + lm][ks * 32 + lk * 8]);
            acc = __builtin_amdgcn_mfma_f32_16x16x32_bf16(af, bfrag[ks], acc, 0, 0, 0);
        }
#pragma unroll
        for (int r = 0; r < 4; r++)
            ctile[mt * 16 + lk * 4 + r][wid * 16 + lm] = acc[r];   // C[m][n]
    }
    __syncthreads();

    int px = t >> 2, jq = t & 3;
    us8 o0, o1;
#pragma unroll
    for (int i = 0; i < 8; i++) {
        o0[i] = f2bf(ctile[px][jq * 16 + i]);
        o1[i] = f2bf(ctile[px][jq * 16 + 8 + i]);
    }
    unsigned short* dst = cpp + ((size_t)(b * 66 + h + 1) * 66 + (px + 1)) * 64 + jq * 16;
    *(us8*)dst = o0;
    *(us8*)(dst + 8) = o1;
}

// FUSED mask+out. grid 512 = (b,h) swizzled; block 384 = 6 waves.
// Phase A unchanged (R13). Phase B: (p_, wp) lane map, f4 stores.
__global__ __launch_bounds__(384) void k_fused(const float* __restrict__ x,
                                               const float* __restrict__ b2,
                                               const float* __restrict__ ws,
                                               float* __restrict__ out) {
    const unsigned short* w2b = (const unsigned short*)(ws + W2B_OFF);
    const unsigned short* cpp = (const unsigned short*)(ws + CPP_OFF);
    const float* mean = ws + MEAN_OFF;
    __shared__ float kern[64][49];
    __shared__ float msk[64][37];

    int bid = blockIdx.x;
    int swz = (bid & 7) * 64 + (bid >> 3);             // XCD chunking, bijective
    int b = swz >> 6, h = swz & 63;
    int t = threadIdx.x;
    int wid = __builtin_amdgcn_readfirstlane(t >> 6);  // 0..5, wave-uniform
    int l = t & 63;

    // ---- Phase A: kern GEMM (M=64 px, N=48, K=576) ----
    {
        int o = wid % 3, ph = wid / 3;
        int lm = l & 15, lk = l >> 4;
        bf8 bfrag[18];
        const unsigned short* bp = w2b + (size_t)(o * 16 + lm) * 576 + lk * 8;
#pragma unroll
        for (int ks = 0; ks < 18; ks++) bfrag[ks] = *(const bf8*)(bp + ks * 32);

        const unsigned short* abase = cpp + ((size_t)(b * 66 + h) * 66 + lm) * 64 + lk * 8;
#pragma unroll
        for (int hf = 0; hf < 2; hf++) {
            int w0 = (ph * 2 + hf) * 16;
            const unsigned short* ab = abase + w0 * 64;
            f4 acc = {0.f, 0.f, 0.f, 0.f};
#pragma unroll
            for (int ks = 0; ks < 18; ks++) {
                const int s = ks >> 1, jh = ks & 1;
                const int dy = s / 3, dx = s % 3;
                bf8 af = *(const bf8*)(ab + (dy * 66 + dx) * 64 + jh * 32);
                acc = __builtin_amdgcn_mfma_f32_16x16x32_bf16(af, bfrag[ks], acc, 0, 0, 0);
            }
#pragma unroll
            for (int r = 0; r < 4; r++)
                kern[w0 + lk * 4 + r][o * 16 + lm] = acc[r];
        }
    }
    __syncthreads();

    // grad guidance + softmax -> msk LDS; thread (w, pq) for t < 256
    if (t < 256) {
        int w = t & 63, pq = t >> 6;
        float mc = mean[(b * 64 + h) * 64 + w];
        float v[9], mx = -1e30f;
#pragma unroll
        for (int kk = 0; kk < 9; kk++) {
            int y = h + kk / 3 - 1, xw = w + kk % 3 - 1;
            float mv = ((unsigned)y < 64u && (unsigned)xw < 64u)
                           ? mean[(b * 64 + y) * 64 + xw] : 0.f;
            float d = mv - mc;
            float g = 1.f / (d * d + 0.2f);
            v[kk] = g * (kern[w][kk * 4 + pq] + b2[kk * 4 + pq]);
            mx = fmaxf(mx, v[kk]);
        }
        float s = 0.f;
#pragma unroll
        for (int kk = 0; kk < 9; kk++) { v[kk] = __expf(v[kk] - mx); s += v[kk]; }
        float inv = 1.f / s;
#pragma unroll
        for (int kk = 0; kk < 9; kk++) msk[w][pq * 9 + kk] = v[kk] * inv;
    }
    __syncthreads();

    // ---- Phase B: reassembly; (p_, wp) map; f4 (16B) stores ----
    int wv = t >> 6;                 // 0..5: c-slot
    int p_ = l >> 5, wp = l & 31;    // row 2h+p_, output cols 4wp..4wp+3

    float m[2][2][9];                // [i = w-offset][q][kk], static indices
#pragma unroll
    for (int i = 0; i < 2; i++)
#pragma unroll
        for (int q = 0; q < 2; q++)
#pragma unroll
            for (int kk = 0; kk < 9; kk++)
                m[i][q][kk] = msk[2 * wp + i][(2 * p_ + q) * 9 + kk];

    for (int c = wv; c < 256; c += 6) {
        const float* xb = x + (size_t)(b * 256 + c) * 4096;
        float p[3][4];               // rows h-1..h+1, cols 2wp-1..2wp+2
#pragma unroll
        for (int dy = 0; dy < 3; dy++) {
            int y = h + dy - 1;
            bool yok = (unsigned)y < 64u;
            float cv = yok ? xb[y * 64 + l] : 0.f;     // coalesced by lane l
#pragma unroll
            for (int dxx = 0; dxx < 4; dxx++) {
                int col = 2 * wp - 1 + dxx;
                int src = col < 0 ? 0 : (col > 63 ? 63 : col);
                float v = __shfl(cv, src);
                p[dy][dxx] = ((unsigned)col < 64u) ? v : 0.f;
            }
        }
        float o00 = 0.f, o01 = 0.f, o10 = 0.f, o11 = 0.f;
#pragma unroll
        for (int kk = 0; kk < 9; kk++) {
            float pv0 = p[kk / 3][kk % 3];      // w = 2wp
            float pv1 = p[kk / 3][kk % 3 + 1];  // w = 2wp+1
            o00 += pv0 * m[0][0][kk];
            o01 += pv0 * m[0][1][kk];
            o10 += pv1 * m[1][0][kk];
            o11 += pv1 * m[1][1][kk];
        }
        float* ob = out + ((size_t)(b * 256 + c) * 128 + 2 * h + p_) * 128 + 4 * wp;
        *(f4*)ob = f4{o00, o01, o10, o11};
    }
}

extern "C" void kernel_launch(void* const* d_in, const int* in_sizes, int n_in,
                              void* d_out, int out_size, void* d_ws, size_t ws_size,
                              hipStream_t stream) {
    const float* x  = (const float*)d_in[0];
    const float* w1 = (const float*)d_in[1];
    const float* b1 = (const float*)d_in[2];
    const float* w2 = (const float*)d_in[3];
    const float* b2 = (const float*)d_in[4];
    float* out = (float*)d_out;
    float* ws  = (float*)d_ws;

    k_init<<<133, 256, 0, stream>>>(w1, w2, ws);
    k_comp<<<512, 256, 0, stream>>>(x, b1, ws);
    k_fused<<<512, 384, 0, stream>>>(x, b2, ws, out);
}

// Round 16
// 68.386 us; speedup vs baseline: 1.0718x; 1.0718x over previous
//
#include <hip/hip_runtime.h>

// GGCARAFE: gradient-guided CARAFE upsample, B=8, C=256, H=W=64, K=3, S=2
// R16 = R13 k_comp/k_init verbatim + k_fused split into HALF-ROW blocks:
//   grid 1024 = (b,h,half), block 192 = 3 waves, LDS 11KB -> 4 blocks/CU.
//   Blocks desync -> one block's Phase-B stores overlap another's Phase-A
//   compute (fillBuffer proves ~3 waves/CU suffice for 6.9 TB/s stores).
//   NO redundant work (R8 lesson); same total MFMA/softmax/stores.
// R15 lesson: f4-store lane map negative (shfl VALU > store-width gain).
// ws layout (float indices):
//   w1bf  [64][256] bf16        @ 0       (8192 f32-equiv)
//   mean  [B][H][W] f32         @ 8192    (32768)
//   w2b   [48][576] bf16        @ 40960   (13824 f32-equiv)
//   comp_p[8][66][66][64] bf16  @ 54784   (1115136 f32-equiv) zero ring
// total 1,169,920 floats = 4.68 MB

#define W1BF_OFF  0
#define MEAN_OFF  8192
#define W2B_OFF   40960
#define CPP_OFF   54784

typedef __attribute__((ext_vector_type(8))) short bf8;            // 8 bf16 = 16B
typedef __attribute__((ext_vector_type(8))) unsigned short us8;   // 16B store
typedef __attribute__((ext_vector_type(4))) float f4;
typedef __attribute__((ext_vector_type(2))) float f2;

static __device__ inline unsigned short f2bf(float f) {
    unsigned u = __float_as_uint(f);
    unsigned r = u + 0x7FFFu + ((u >> 16) & 1u);   // RNE
    return (unsigned short)(r >> 16);
}

// k_init: zero comp_p PAD RING only + weight converts/transposes.
__global__ __launch_bounds__(256) void k_init(const float* __restrict__ w1,
                                              const float* __restrict__ w2,
                                              float* __restrict__ ws) {
    int bid = blockIdx.x, t = threadIdx.x;
    if (bid < 65) {
        int id = bid * 256 + t;           // 0..16639
        if (id < 16640) {
            int px = id >> 3, part = id & 7;
            int b = px / 260, r = px % 260;
            int y, xx;
            if (r < 66)       { y = 0;  xx = r; }
            else if (r < 132) { y = 65; xx = r - 66; }
            else              { int s = r - 132; y = (s & 63) + 1; xx = (s >> 6) ? 65 : 0; }
            uint4* p = (uint4*)((unsigned short*)(ws + CPP_OFF)
                                + ((size_t)(b * 66 + y) * 66 + xx) * 64) + part;
            *p = uint4{0, 0, 0, 0};
        }
        return;
    }
    unsigned short* w1bf = (unsigned short*)(ws + W1BF_OFF);
    unsigned short* w2b  = (unsigned short*)(ws + W2B_OFF);
    int gid = (bid - 65) * 256 + t;
    int stride = 68 * 256;
    for (int i = gid; i < 64 * 256; i += stride)         // direct convert
        w1bf[i] = f2bf(w1[i]);
    for (int i = gid; i < 48 * 576; i += stride) {       // w2b[o][s*64+j]
        int o = i / 576, k = i % 576;
        int s = k >> 6, j = k & 63;
        w2b[i] = (o < 36) ? f2bf(w2[o * 576 + j * 9 + s]) : (unsigned short)0;
    }
}

// comp GEMM (R13 proven): grid 512 = (b,h); block 256 = 4 waves.
__global__ __launch_bounds__(256) void k_comp(const float* __restrict__ x,
                                              const float* __restrict__ b1,
                                              float* __restrict__ ws) {
    const unsigned short* w1bf = (const unsigned short*)(ws + W1BF_OFF);
    float* mean = ws + MEAN_OFF;
    unsigned short* cpp = (unsigned short*)(ws + CPP_OFF);
    __shared__ unsigned short xbf[64][260];   // 33.3 KB (+4 pad)
    __shared__ float msp[16][64];             // 4 KB mean partials
    __shared__ float ctile[64][68];           // 17.4 KB epilogue staging

    int bid = blockIdx.x;
    int b = bid >> 6, h = bid & 63;
    int t = threadIdx.x;

    int cg = t >> 4;
    int px4 = (t & 15) * 4;
    float ms0 = 0.f, ms1 = 0.f, ms2 = 0.f, ms3 = 0.f;
    const float* xb = x + (size_t)b * 256 * 4096 + h * 64;
#pragma unroll
    for (int it = 0; it < 16; it++) {
        int c = it * 16 + cg;
        f4 v = *(const f4*)(xb + (size_t)c * 4096 + px4);
        ms0 += v[0]; ms1 += v[1]; ms2 += v[2]; ms3 += v[3];
        xbf[px4 + 0][c] = f2bf(v[0]);
        xbf[px4 + 1][c] = f2bf(v[1]);
        xbf[px4 + 2][c] = f2bf(v[2]);
        xbf[px4 + 3][c] = f2bf(v[3]);
    }
    msp[cg][px4 + 0] = ms0; msp[cg][px4 + 1] = ms1;
    msp[cg][px4 + 2] = ms2; msp[cg][px4 + 3] = ms3;
    __syncthreads();
    if (t < 64) {
        float s = 0.f;
#pragma unroll
        for (int k2 = 0; k2 < 16; k2++) s += msp[k2][t];
        mean[(b * 64 + h) * 64 + t] = s * (1.f / 256.f);
    }

    int wid = __builtin_amdgcn_readfirstlane(t >> 6);  // 0..3
    int l = t & 63, lm = l & 15, lk = l >> 4;
    bf8 bfrag[8];
    const unsigned short* wp = w1bf + (size_t)(wid * 16 + lm) * 256 + lk * 8;
#pragma unroll
    for (int ks = 0; ks < 8; ks++) bfrag[ks] = *(const bf8*)(wp + ks * 32);
    float bb = b1[wid * 16 + lm];
#pragma unroll
    for (int mt = 0; mt < 4; mt++) {
        f4 acc = {bb, bb, bb, bb};
#pragma unroll
        for (int ks = 0; ks < 8; ks++) {
            bf8 af = *(const bf8*)(&xbf[mt * 16 + lm][ks * 32 + lk * 8]);
            acc = __builtin_amdgcn_mfma_f32_16x16x32_bf16(af, bfrag[ks], acc, 0, 0, 0);
        }
#pragma unroll
        for (int r = 0; r < 4; r++)
            ctile[mt * 16 + lk * 4 + r][wid * 16 + lm] = acc[r];   // C[m][n]
    }
    __syncthreads();

    int px = t >> 2, jq = t & 3;
    us8 o0, o1;
#pragma unroll
    for (int i = 0; i < 8; i++) {
        o0[i] = f2bf(ctile[px][jq * 16 + i]);
        o1[i] = f2bf(ctile[px][jq * 16 + 8 + i]);
    }
    unsigned short* dst = cpp + ((size_t)(b * 66 + h + 1) * 66 + (px + 1)) * 64 + jq * 16;
    *(us8*)dst = o0;
    *(us8*)(dst + 8) = o1;
}

// FUSED mask+out, HALF-ROW blocks. grid 1024 = (b,h,half) swizzled;
// block 192 = 3 waves. Phase A: wave = o-tile (16 n), 2 m-tiles of 16 px.
// softmax on t<128 (32 px x 4 pq). Phase B: lane = (csel=l>>5, w=l&31),
// c-slot = wv*2+csel (6 slots), f2 stores.
__global__ __launch_bounds__(192) void k_fused(const float* __restrict__ x,
                                               const float* __restrict__ b2,
                                               const float* __restrict__ ws,
                                               float* __restrict__ out) {
    const unsigned short* w2b = (const unsigned short*)(ws + W2B_OFF);
    const unsigned short* cpp = (const unsigned short*)(ws + CPP_OFF);
    const float* mean = ws + MEAN_OFF;
    __shared__ float kern[32][49];   // 6.3 KB
    __shared__ float msk[32][37];    // 4.7 KB

    int bid = blockIdx.x;
    int swz = (bid & 7) * 128 + (bid >> 3);            // 1024 = 8 x 128, bijective
    int bh = swz >> 1, half = swz & 1;
    int b = bh >> 6, h = bh & 63;
    int px0 = half * 32;
    int t = threadIdx.x;
    int wid = __builtin_amdgcn_readfirstlane(t >> 6);  // 0..2, wave-uniform
    int l = t & 63;

    // ---- Phase A: kern GEMM (M=32 px, N=48, K=576); wave wid = o-tile ----
    {
        int o = wid;
        int lm = l & 15, lk = l >> 4;
        bf8 bfrag[18];
        const unsigned short* bp = w2b + (size_t)(o * 16 + lm) * 576 + lk * 8;
#pragma unroll
        for (int ks = 0; ks < 18; ks++) bfrag[ks] = *(const bf8*)(bp + ks * 32);

        const unsigned short* abase =
            cpp + ((size_t)(b * 66 + h) * 66 + px0 + lm) * 64 + lk * 8;
#pragma unroll
        for (int mt = 0; mt < 2; mt++) {
            int w0 = mt * 16;
            const unsigned short* ab = abase + w0 * 64;
            f4 acc = {0.f, 0.f, 0.f, 0.f};
#pragma unroll
            for (int ks = 0; ks < 18; ks++) {
                const int s = ks >> 1, jh = ks & 1;
                const int dy = s / 3, dx = s % 3;      // compile-time
                bf8 af = *(const bf8*)(ab + (dy * 66 + dx) * 64 + jh * 32);
                acc = __builtin_amdgcn_mfma_f32_16x16x32_bf16(af, bfrag[ks], acc, 0, 0, 0);
            }
#pragma unroll
            for (int r = 0; r < 4; r++)
                kern[w0 + lk * 4 + r][o * 16 + lm] = acc[r];
        }
    }
    __syncthreads();

    // grad guidance + softmax -> msk LDS; thread (w, pq) for t < 128
    if (t < 128) {
        int w = t & 31, pq = t >> 5;
        int wg = px0 + w;
        float mc = mean[(b * 64 + h) * 64 + wg];
        float v[9], mx = -1e30f;
#pragma unroll
        for (int kk = 0; kk < 9; kk++) {
            int y = h + kk / 3 - 1, xw = wg + kk % 3 - 1;
            float mv = ((unsigned)y < 64u && (unsigned)xw < 64u)
                           ? mean[(b * 64 + y) * 64 + xw] : 0.f;
            float d = mv - mc;
            float g = 1.f / (d * d + 0.2f);
            v[kk] = g * (kern[w][kk * 4 + pq] + b2[kk * 4 + pq]);
            mx = fmaxf(mx, v[kk]);
        }
        float s = 0.f;
#pragma unroll
        for (int kk = 0; kk < 9; kk++) { v[kk] = __expf(v[kk] - mx); s += v[kk]; }
        float inv = 1.f / s;
#pragma unroll
        for (int kk = 0; kk < 9; kk++) msk[w][pq * 9 + kk] = v[kk] * inv;
    }
    __syncthreads();

    // ---- Phase B: reassembly; lane = (csel, w); f2 stores ----
    int wv = t >> 6;                 // 0..2
    int csel = l >> 5;               // 0..1
    int w = l & 31;
    int wg = px0 + w;

    float m[4][9];
#pragma unroll
    for (int pq = 0; pq < 4; pq++)
#pragma unroll
        for (int kk = 0; kk < 9; kk++) m[pq][kk] = msk[w][pq * 9 + kk];

    for (int c = wv * 2 + csel; c < 256; c += 6) {
        const float* xb = x + (size_t)(b * 256 + c) * 4096;
        float p[3][3];
#pragma unroll
        for (int dy = 0; dy < 3; dy++) {
            int y = h + dy - 1;
            bool yok = (unsigned)y < 64u;
#pragma unroll
            for (int dx = 0; dx < 3; dx++) {
                int xx = wg + dx - 1;
                p[dy][dx] = (yok && (unsigned)xx < 64u) ? xb[y * 64 + xx] : 0.f;
            }
        }
        float o00 = 0.f, o01 = 0.f, o10 = 0.f, o11 = 0.f;
#pragma unroll
        for (int kk = 0; kk < 9; kk++) {
            float pv = p[kk / 3][kk % 3];
            o00 += pv * m[0][kk];
            o01 += pv * m[1][kk];
            o10 += pv * m[2][kk];
            o11 += pv * m[3][kk];
        }
        float* ob = out + ((size_t)(b * 256 + c) * 128 + 2 * h) * 128 + 2 * wg;
        *(f2*)ob = f2{o00, o01};             // row 2h   (p=0)
        *(f2*)(ob + 128) = f2{o10, o11};     // row 2h+1 (p=1)
    }
}

extern "C" void kernel_launch(void* const* d_in, const int* in_sizes, int n_in,
                              void* d_out, int out_size, void* d_ws, size_t ws_size,
                              hipStream_t stream) {
    const float* x  = (const float*)d_in[0];
    const float* w1 = (const float*)d_in[1];
    const float* b1 = (const float*)d_in[2];
    const float* w2 = (const float*)d_in[3];
    const float* b2 = (const float*)d_in[4];
    float* out = (float*)d_out;
    float* ws  = (float*)d_ws;

    k_init<<<133, 256, 0, stream>>>(w1, w2, ws);
    k_comp<<<512, 256, 0, stream>>>(x, b1, ws);
    k_fused<<<1024, 192, 0, stream>>>(x, b2, ws, out);
}

// Round 17
// 68.025 us; speedup vs baseline: 1.0775x; 1.0053x over previous
//
#include <hip/hip_runtime.h>

// GGCARAFE: gradient-guided CARAFE upsample, B=8, C=256, H=W=64, K=3, S=2
// R17 = R13 + k_fused __launch_bounds__(384,1) + unroll-2 Phase B c-loop.
//   R8 counters: k_fused VGPR=40 (!) with m[36]+p[9] live -> compiler was
//   occupancy-minimizing registers, re-reading msk LDS + recomputing
//   addresses EVERY iter and blocking cross-iter ILP. All four memory-side
//   theories (R11/R14/R15/R16) null because the bind is issue/latency from
//   register starvation. Free the allocator; give it 2 iters of ILP.
// ws layout (float indices):
//   w1bf  [64][256] bf16        @ 0       (8192 f32-equiv)
//   mean  [B][H][W] f32         @ 8192    (32768)
//   w2b   [48][576] bf16        @ 40960   (13824 f32-equiv)
//   comp_p[8][66][66][64] bf16  @ 54784   (1115136 f32-equiv) zero ring
// total 1,169,920 floats = 4.68 MB

#define W1BF_OFF  0
#define MEAN_OFF  8192
#define W2B_OFF   40960
#define CPP_OFF   54784

typedef __attribute__((ext_vector_type(8))) short bf8;            // 8 bf16 = 16B
typedef __attribute__((ext_vector_type(8))) unsigned short us8;   // 16B store
typedef __attribute__((ext_vector_type(4))) float f4;
typedef __attribute__((ext_vector_type(2))) float f2;

static __device__ inline unsigned short f2bf(float f) {
    unsigned u = __float_as_uint(f);
    unsigned r = u + 0x7FFFu + ((u >> 16) & 1u);   // RNE
    return (unsigned short)(r >> 16);
}

// k_init: zero comp_p PAD RING only + weight converts/transposes.
__global__ __launch_bounds__(256) void k_init(const float* __restrict__ w1,
                                              const float* __restrict__ w2,
                                              float* __restrict__ ws) {
    int bid = blockIdx.x, t = threadIdx.x;
    if (bid < 65) {
        int id = bid * 256 + t;           // 0..16639
        if (id < 16640) {
            int px = id >> 3, part = id & 7;
            int b = px / 260, r = px % 260;
            int y, xx;
            if (r < 66)       { y = 0;  xx = r; }
            else if (r < 132) { y = 65; xx = r - 66; }
            else              { int s = r - 132; y = (s & 63) + 1; xx = (s >> 6) ? 65 : 0; }
            uint4* p = (uint4*)((unsigned short*)(ws + CPP_OFF)
                                + ((size_t)(b * 66 + y) * 66 + xx) * 64) + part;
            *p = uint4{0, 0, 0, 0};
        }
        return;
    }
    unsigned short* w1bf = (unsigned short*)(ws + W1BF_OFF);
    unsigned short* w2b  = (unsigned short*)(ws + W2B_OFF);
    int gid = (bid - 65) * 256 + t;
    int stride = 68 * 256;
    for (int i = gid; i < 64 * 256; i += stride)         // direct convert
        w1bf[i] = f2bf(w1[i]);
    for (int i = gid; i < 48 * 576; i += stride) {       // w2b[o][s*64+j]
        int o = i / 576, k = i % 576;
        int s = k >> 6, j = k & 63;
        w2b[i] = (o < 36) ? f2bf(w2[o * 576 + j * 9 + s]) : (unsigned short)0;
    }
}

// comp GEMM (R13 proven): grid 512 = (b,h); block 256 = 4 waves.
__global__ __launch_bounds__(256) void k_comp(const float* __restrict__ x,
                                              const float* __restrict__ b1,
                                              float* __restrict__ ws) {
    const unsigned short* w1bf = (const unsigned short*)(ws + W1BF_OFF);
    float* mean = ws + MEAN_OFF;
    unsigned short* cpp = (unsigned short*)(ws + CPP_OFF);
    __shared__ unsigned short xbf[64][260];   // 33.3 KB (+4 pad)
    __shared__ float msp[16][64];             // 4 KB mean partials
    __shared__ float ctile[64][68];           // 17.4 KB epilogue staging

    int bid = blockIdx.x;
    int b = bid >> 6, h = bid & 63;
    int t = threadIdx.x;

    int cg = t >> 4;
    int px4 = (t & 15) * 4;
    float ms0 = 0.f, ms1 = 0.f, ms2 = 0.f, ms3 = 0.f;
    const float* xb = x + (size_t)b * 256 * 4096 + h * 64;
#pragma unroll
    for (int it = 0; it < 16; it++) {
        int c = it * 16 + cg;
        f4 v = *(const f4*)(xb + (size_t)c * 4096 + px4);
        ms0 += v[0]; ms1 += v[1]; ms2 += v[2]; ms3 += v[3];
        xbf[px4 + 0][c] = f2bf(v[0]);
        xbf[px4 + 1][c] = f2bf(v[1]);
        xbf[px4 + 2][c] = f2bf(v[2]);
        xbf[px4 + 3][c] = f2bf(v[3]);
    }
    msp[cg][px4 + 0] = ms0; msp[cg][px4 + 1] = ms1;
    msp[cg][px4 + 2] = ms2; msp[cg][px4 + 3] = ms3;
    __syncthreads();
    if (t < 64) {
        float s = 0.f;
#pragma unroll
        for (int k2 = 0; k2 < 16; k2++) s += msp[k2][t];
        mean[(b * 64 + h) * 64 + t] = s * (1.f / 256.f);
    }

    int wid = __builtin_amdgcn_readfirstlane(t >> 6);  // 0..3
    int l = t & 63, lm = l & 15, lk = l >> 4;
    bf8 bfrag[8];
    const unsigned short* wp = w1bf + (size_t)(wid * 16 + lm) * 256 + lk * 8;
#pragma unroll
    for (int ks = 0; ks < 8; ks++) bfrag[ks] = *(const bf8*)(wp + ks * 32);
    float bb = b1[wid * 16 + lm];
#pragma unroll
    for (int mt = 0; mt < 4; mt++) {
        f4 acc = {bb, bb, bb, bb};
#pragma unroll
        for (int ks = 0; ks < 8; ks++) {
            bf8 af = *(const bf8*)(&xbf[mt * 16 + lm][ks * 32 + lk * 8]);
            acc = __builtin_amdgcn_mfma_f32_16x16x32_bf16(af, bfrag[ks], acc, 0, 0, 0);
        }
#pragma unroll
        for (int r = 0; r < 4; r++)
            ctile[mt * 16 + lk * 4 + r][wid * 16 + lm] = acc[r];   // C[m][n]
    }
    __syncthreads();

    int px = t >> 2, jq = t & 3;
    us8 o0, o1;
#pragma unroll
    for (int i = 0; i < 8; i++) {
        o0[i] = f2bf(ctile[px][jq * 16 + i]);
        o1[i] = f2bf(ctile[px][jq * 16 + 8 + i]);
    }
    unsigned short* dst = cpp + ((size_t)(b * 66 + h + 1) * 66 + (px + 1)) * 64 + jq * 16;
    *(us8*)dst = o0;
    *(us8*)(dst + 8) = o1;
}

// FUSED mask+out. grid 512 = (b,h) swizzled; block 384 = 6 waves.
// __launch_bounds__(384, 1): let the allocator keep m[36]+patches in VGPRs.
__global__ __launch_bounds__(384, 1) void k_fused(const float* __restrict__ x,
                                                  const float* __restrict__ b2,
                                                  const float* __restrict__ ws,
                                                  float* __restrict__ out) {
    const unsigned short* w2b = (const unsigned short*)(ws + W2B_OFF);
    const unsigned short* cpp = (const unsigned short*)(ws + CPP_OFF);
    const float* mean = ws + MEAN_OFF;
    __shared__ float kern[64][49];
    __shared__ float msk[64][37];

    int bid = blockIdx.x;
    int swz = (bid & 7) * 64 + (bid >> 3);             // XCD chunking, bijective
    int b = swz >> 6, h = swz & 63;
    int t = threadIdx.x;
    int wid = __builtin_amdgcn_readfirstlane(t >> 6);  // 0..5, wave-uniform
    int l = t & 63;

    // ---- Phase A: kern GEMM (M=64 px, N=48, K=576) ----
    {
        int o = wid % 3, ph = wid / 3;
        int lm = l & 15, lk = l >> 4;
        bf8 bfrag[18];
        const unsigned short* bp = w2b + (size_t)(o * 16 + lm) * 576 + lk * 8;
#pragma unroll
        for (int ks = 0; ks < 18; ks++) bfrag[ks] = *(const bf8*)(bp + ks * 32);

        const unsigned short* abase = cpp + ((size_t)(b * 66 + h) * 66 + lm) * 64 + lk * 8;
#pragma unroll
        for (int hf = 0; hf < 2; hf++) {
            int w0 = (ph * 2 + hf) * 16;
            const unsigned short* ab = abase + w0 * 64;
            f4 acc = {0.f, 0.f, 0.f, 0.f};
#pragma unroll
            for (int ks = 0; ks < 18; ks++) {
                const int s = ks >> 1, jh = ks & 1;
                const int dy = s / 3, dx = s % 3;
                bf8 af = *(const bf8*)(ab + (dy * 66 + dx) * 64 + jh * 32);
                acc = __builtin_amdgcn_mfma_f32_16x16x32_bf16(af, bfrag[ks], acc, 0, 0, 0);
            }
#pragma unroll
            for (int r = 0; r < 4; r++)
                kern[w0 + lk * 4 + r][o * 16 + lm] = acc[r];
        }
    }
    __syncthreads();

    // grad guidance + softmax -> msk LDS; thread (w, pq) for t < 256
    if (t < 256) {
        int w = t & 63, pq = t >> 6;
        float mc = mean[(b * 64 + h) * 64 + w];
        float v[9], mx = -1e30f;
#pragma unroll
        for (int kk = 0; kk < 9; kk++) {
            int y = h + kk / 3 - 1, xw = w + kk % 3 - 1;
            float mv = ((unsigned)y < 64u && (unsigned)xw < 64u)
                           ? mean[(b * 64 + y) * 64 + xw] : 0.f;
            float d = mv - mc;
            float g = 1.f / (d * d + 0.2f);
            v[kk] = g * (kern[w][kk * 4 + pq] + b2[kk * 4 + pq]);
            mx = fmaxf(mx, v[kk]);
        }
        float s = 0.f;
#pragma unroll
        for (int kk = 0; kk < 9; kk++) { v[kk] = __expf(v[kk] - mx); s += v[kk]; }
        float inv = 1.f / s;
#pragma unroll
        for (int kk = 0; kk < 9; kk++) msk[w][pq * 9 + kk] = v[kk] * inv;
    }
    __syncthreads();

    // ---- Phase B: reassembly, f2 stores, unroll 2 for cross-iter ILP ----
    int wv = t >> 6;                 // 0..5: c-slot
    int w = l;

    float m[4][9];
#pragma unroll
    for (int pq = 0; pq < 4; pq++)
#pragma unroll
        for (int kk = 0; kk < 9; kk++) m[pq][kk] = msk[w][pq * 9 + kk];

#pragma unroll 2
    for (int c = wv; c < 256; c += 6) {
        const float* xb = x + (size_t)(b * 256 + c) * 4096;
        float p[3][3];
#pragma unroll
        for (int dy = 0; dy < 3; dy++) {
            int y = h + dy - 1;
            bool yok = (unsigned)y < 64u;
#pragma unroll
            for (int dx = 0; dx < 3; dx++) {
                int xx = w + dx - 1;
                p[dy][dx] = (yok && (unsigned)xx < 64u) ? xb[y * 64 + xx] : 0.f;
            }
        }
        float o00 = 0.f, o01 = 0.f, o10 = 0.f, o11 = 0.f;
#pragma unroll
        for (int kk = 0; kk < 9; kk++) {
            float pv = p[kk / 3][kk % 3];
            o00 += pv * m[0][kk];
            o01 += pv * m[1][kk];
            o10 += pv * m[2][kk];
            o11 += pv * m[3][kk];
        }
        float* ob = out + ((size_t)(b * 256 + c) * 128 + 2 * h) * 128 + 2 * w;
        *(f2*)ob = f2{o00, o01};             // row 2h   (p=0)
        *(f2*)(ob + 128) = f2{o10, o11};     // row 2h+1 (p=1)
    }
}

extern "C" void kernel_launch(void* const* d_in, const int* in_sizes, int n_in,
                              void* d_out, int out_size, void* d_ws, size_t ws_size,
                              hipStream_t stream) {
    const float* x  = (const float*)d_in[0];
    const float* w1 = (const float*)d_in[1];
    const float* b1 = (const float*)d_in[2];
    const float* w2 = (const float*)d_in[3];
    const float* b2 = (const float*)d_in[4];
    float* out = (float*)d_out;
    float* ws  = (float*)d_ws;

    k_init<<<133, 256, 0, stream>>>(w1, w2, ws);
    k_comp<<<512, 256, 0, stream>>>(x, b1, ws);
    k_fused<<<512, 384, 0, stream>>>(x, b2, ws, out);
}

// Round 18
// 67.716 us; speedup vs baseline: 1.0824x; 1.0046x over previous
//
#include <hip/hip_runtime.h>

// GGCARAFE: gradient-guided CARAFE upsample, B=8, C=256, H=W=64, K=3, S=2
// R18 = R13 + ONE line: k_comp gets the SAME XCD swizzle as k_fused.
//   Audit finding: k_fused's swizzle maps batch b -> XCD b, but k_comp was
//   unswizzled (row (b,h) -> XCD h%8) => every comp_p/mean read in k_fused
//   Phase A was a cross-XCD L2 miss on the serial load->MFMA->softmax chain.
//   Five Phase-B probes (R11/R14/R15/R16/R17) were null because the latency
//   lives in Phase A's cross-XCD reads. Now batch b is produced AND consumed
//   on XCD b (x 4.2MB + comp_p 1.1MB ≈ L2 per XCD).
// ws layout (float indices):
//   w1bf  [64][256] bf16        @ 0       (8192 f32-equiv)
//   mean  [B][H][W] f32         @ 8192    (32768)
//   w2b   [48][576] bf16        @ 40960   (13824 f32-equiv)
//   comp_p[8][66][66][64] bf16  @ 54784   (1115136 f32-equiv) zero ring
// total 1,169,920 floats = 4.68 MB

#define W1BF_OFF  0
#define MEAN_OFF  8192
#define W2B_OFF   40960
#define CPP_OFF   54784

typedef __attribute__((ext_vector_type(8))) short bf8;            // 8 bf16 = 16B
typedef __attribute__((ext_vector_type(8))) unsigned short us8;   // 16B store
typedef __attribute__((ext_vector_type(4))) float f4;
typedef __attribute__((ext_vector_type(2))) float f2;

static __device__ inline unsigned short f2bf(float f) {
    unsigned u = __float_as_uint(f);
    unsigned r = u + 0x7FFFu + ((u >> 16) & 1u);   // RNE
    return (unsigned short)(r >> 16);
}

// k_init: zero comp_p PAD RING only + weight converts/transposes.
__global__ __launch_bounds__(256) void k_init(const float* __restrict__ w1,
                                              const float* __restrict__ w2,
                                              float* __restrict__ ws) {
    int bid = blockIdx.x, t = threadIdx.x;
    if (bid < 65) {
        int id = bid * 256 + t;           // 0..16639
        if (id < 16640) {
            int px = id >> 3, part = id & 7;
            int b = px / 260, r = px % 260;
            int y, xx;
            if (r < 66)       { y = 0;  xx = r; }
            else if (r < 132) { y = 65; xx = r - 66; }
            else              { int s = r - 132; y = (s & 63) + 1; xx = (s >> 6) ? 65 : 0; }
            uint4* p = (uint4*)((unsigned short*)(ws + CPP_OFF)
                                + ((size_t)(b * 66 + y) * 66 + xx) * 64) + part;
            *p = uint4{0, 0, 0, 0};
        }
        return;
    }
    unsigned short* w1bf = (unsigned short*)(ws + W1BF_OFF);
    unsigned short* w2b  = (unsigned short*)(ws + W2B_OFF);
    int gid = (bid - 65) * 256 + t;
    int stride = 68 * 256;
    for (int i = gid; i < 64 * 256; i += stride)         // direct convert
        w1bf[i] = f2bf(w1[i]);
    for (int i = gid; i < 48 * 576; i += stride) {       // w2b[o][s*64+j]
        int o = i / 576, k = i % 576;
        int s = k >> 6, j = k & 63;
        w2b[i] = (o < 36) ? f2bf(w2[o * 576 + j * 9 + s]) : (unsigned short)0;
    }
}

// comp GEMM (R13 structure): grid 512 = (b,h) SWIZZLED to match k_fused
// (batch b -> XCD b), block 256 = 4 waves.
__global__ __launch_bounds__(256) void k_comp(const float* __restrict__ x,
                                              const float* __restrict__ b1,
                                              float* __restrict__ ws) {
    const unsigned short* w1bf = (const unsigned short*)(ws + W1BF_OFF);
    float* mean = ws + MEAN_OFF;
    unsigned short* cpp = (unsigned short*)(ws + CPP_OFF);
    __shared__ unsigned short xbf[64][260];   // 33.3 KB (+4 pad)
    __shared__ float msp[16][64];             // 4 KB mean partials
    __shared__ float ctile[64][68];           // 17.4 KB epilogue staging

    int bid = blockIdx.x;
    int swz = (bid & 7) * 64 + (bid >> 3);    // SAME transform as k_fused
    int b = swz >> 6, h = swz & 63;           // => XCD (bid&7) == b
    int t = threadIdx.x;

    int cg = t >> 4;
    int px4 = (t & 15) * 4;
    float ms0 = 0.f, ms1 = 0.f, ms2 = 0.f, ms3 = 0.f;
    const float* xb = x + (size_t)b * 256 * 4096 + h * 64;
#pragma unroll
    for (int it = 0; it < 16; it++) {
        int c = it * 16 + cg;
        f4 v = *(const f4*)(xb + (size_t)c * 4096 + px4);
        ms0 += v[0]; ms1 += v[1]; ms2 += v[2]; ms3 += v[3];
        xbf[px4 + 0][c] = f2bf(v[0]);
        xbf[px4 + 1][c] = f2bf(v[1]);
        xbf[px4 + 2][c] = f2bf(v[2]);
        xbf[px4 + 3][c] = f2bf(v[3]);
    }
    msp[cg][px4 + 0] = ms0; msp[cg][px4 + 1] = ms1;
    msp[cg][px4 + 2] = ms2; msp[cg][px4 + 3] = ms3;
    __syncthreads();
    if (t < 64) {
        float s = 0.f;
#pragma unroll
        for (int k2 = 0; k2 < 16; k2++) s += msp[k2][t];
        mean[(b * 64 + h) * 64 + t] = s * (1.f / 256.f);
    }

    int wid = __builtin_amdgcn_readfirstlane(t >> 6);  // 0..3
    int l = t & 63, lm = l & 15, lk = l >> 4;
    bf8 bfrag[8];
    const unsigned short* wp = w1bf + (size_t)(wid * 16 + lm) * 256 + lk * 8;
#pragma unroll
    for (int ks = 0; ks < 8; ks++) bfrag[ks] = *(const bf8*)(wp + ks * 32);
    float bb = b1[wid * 16 + lm];
#pragma unroll
    for (int mt = 0; mt < 4; mt++) {
        f4 acc = {bb, bb, bb, bb};
#pragma unroll
        for (int ks = 0; ks < 8; ks++) {
            bf8 af = *(const bf8*)(&xbf[mt * 16 + lm][ks * 32 + lk * 8]);
            acc = __builtin_amdgcn_mfma_f32_16x16x32_bf16(af, bfrag[ks], acc, 0, 0, 0);
        }
#pragma unroll
        for (int r = 0; r < 4; r++)
            ctile[mt * 16 + lk * 4 + r][wid * 16 + lm] = acc[r];   // C[m][n]
    }
    __syncthreads();

    int px = t >> 2, jq = t & 3;
    us8 o0, o1;
#pragma unroll
    for (int i = 0; i < 8; i++) {
        o0[i] = f2bf(ctile[px][jq * 16 + i]);
        o1[i] = f2bf(ctile[px][jq * 16 + 8 + i]);
    }
    unsigned short* dst = cpp + ((size_t)(b * 66 + h + 1) * 66 + (px + 1)) * 64 + jq * 16;
    *(us8*)dst = o0;
    *(us8*)(dst + 8) = o1;
}

// FUSED mask+out (R13 verbatim). grid 512 = (b,h) swizzled; block 384 = 6 waves.
__global__ __launch_bounds__(384) void k_fused(const float* __restrict__ x,
                                               const float* __restrict__ b2,
                                               const float* __restrict__ ws,
                                               float* __restrict__ out) {
    const unsigned short* w2b = (const unsigned short*)(ws + W2B_OFF);
    const unsigned short* cpp = (const unsigned short*)(ws + CPP_OFF);
    const float* mean = ws + MEAN_OFF;
    __shared__ float kern[64][49];
    __shared__ float msk[64][37];

    int bid = blockIdx.x;
    int swz = (bid & 7) * 64 + (bid >> 3);             // batch b -> XCD b
    int b = swz >> 6, h = swz & 63;
    int t = threadIdx.x;
    int wid = __builtin_amdgcn_readfirstlane(t >> 6);  // 0..5, wave-uniform
    int l = t & 63;

    // ---- Phase A: kern GEMM (M=64 px, N=48, K=576) ----
    {
        int o = wid % 3, ph = wid / 3;
        int lm = l & 15, lk = l >> 4;
        bf8 bfrag[18];
        const unsigned short* bp = w2b + (size_t)(o * 16 + lm) * 576 + lk * 8;
#pragma unroll
        for (int ks = 0; ks < 18; ks++) bfrag[ks] = *(const bf8*)(bp + ks * 32);

        const unsigned short* abase = cpp + ((size_t)(b * 66 + h) * 66 + lm) * 64 + lk * 8;
#pragma unroll
        for (int hf = 0; hf < 2; hf++) {
            int w0 = (ph * 2 + hf) * 16;
            const unsigned short* ab = abase + w0 * 64;
            f4 acc = {0.f, 0.f, 0.f, 0.f};
#pragma unroll
            for (int ks = 0; ks < 18; ks++) {
                const int s = ks >> 1, jh = ks & 1;
                const int dy = s / 3, dx = s % 3;
                bf8 af = *(const bf8*)(ab + (dy * 66 + dx) * 64 + jh * 32);
                acc = __builtin_amdgcn_mfma_f32_16x16x32_bf16(af, bfrag[ks], acc, 0, 0, 0);
            }
#pragma unroll
            for (int r = 0; r < 4; r++)
                kern[w0 + lk * 4 + r][o * 16 + lm] = acc[r];
        }
    }
    __syncthreads();

    // grad guidance + softmax -> msk LDS; thread (w, pq) for t < 256
    if (t < 256) {
        int w = t & 63, pq = t >> 6;
        float mc = mean[(b * 64 + h) * 64 + w];
        float v[9], mx = -1e30f;
#pragma unroll
        for (int kk = 0; kk < 9; kk++) {
            int y = h + kk / 3 - 1, xw = w + kk % 3 - 1;
            float mv = ((unsigned)y < 64u && (unsigned)xw < 64u)
                           ? mean[(b * 64 + y) * 64 + xw] : 0.f;
            float d = mv - mc;
            float g = 1.f / (d * d + 0.2f);
            v[kk] = g * (kern[w][kk * 4 + pq] + b2[kk * 4 + pq]);
            mx = fmaxf(mx, v[kk]);
        }
        float s = 0.f;
#pragma unroll
        for (int kk = 0; kk < 9; kk++) { v[kk] = __expf(v[kk] - mx); s += v[kk]; }
        float inv = 1.f / s;
#pragma unroll
        for (int kk = 0; kk < 9; kk++) msk[w][pq * 9 + kk] = v[kk] * inv;
    }
    __syncthreads();

    // ---- Phase B: reassembly, f2 stores ----
    int wv = t >> 6;                 // 0..5: c-slot
    int w = l;

    float m[4][9];
#pragma unroll
    for (int pq = 0; pq < 4; pq++)
#pragma unroll
        for (int kk = 0; kk < 9; kk++) m[pq][kk] = msk[w][pq * 9 + kk];

    for (int c = wv; c < 256; c += 6) {
        const float* xb = x + (size_t)(b * 256 + c) * 4096;
        float p[3][3];
#pragma unroll
        for (int dy = 0; dy < 3; dy++) {
            int y = h + dy - 1;
            bool yok = (unsigned)y < 64u;
#pragma unroll
            for (int dx = 0; dx < 3; dx++) {
                int xx = w + dx - 1;
                p[dy][dx] = (yok && (unsigned)xx < 64u) ? xb[y * 64 + xx] : 0.f;
            }
        }
        float o00 = 0.f, o01 = 0.f, o10 = 0.f, o11 = 0.f;
#pragma unroll
        for (int kk = 0; kk < 9; kk++) {
            float pv = p[kk / 3][kk % 3];
            o00 += pv * m[0][kk];
            o01 += pv * m[1][kk];
            o10 += pv * m[2][kk];
            o11 += pv * m[3][kk];
        }
        float* ob = out + ((size_t)(b * 256 + c) * 128 + 2 * h) * 128 + 2 * w;
        *(f2*)ob = f2{o00, o01};             // row 2h   (p=0)
        *(f2*)(ob + 128) = f2{o10, o11};     // row 2h+1 (p=1)
    }
}

extern "C" void kernel_launch(void* const* d_in, const int* in_sizes, int n_in,
                              void* d_out, int out_size, void* d_ws, size_t ws_size,
                              hipStream_t stream) {
    const float* x  = (const float*)d_in[0];
    const float* w1 = (const float*)d_in[1];
    const float* b1 = (const float*)d_in[2];
    const float* w2 = (const float*)d_in[3];
    const float* b2 = (const float*)d_in[4];
    float* out = (float*)d_out;
    float* ws  = (float*)d_ws;

    k_init<<<133, 256, 0, stream>>>(w1, w2, ws);
    k_comp<<<512, 256, 0, stream>>>(x, b1, ws);
    k_fused<<<512, 384, 0, stream>>>(x, b2, ws, out);
}